// Round 1
// baseline (803.991 us; speedup 1.0000x reference)
//
#include <hip/hip_runtime.h>
#include <cstdint>

#define BATCH 512
#define CIN   64
#define HH    32
#define WW    64
#define HW    2048
#define C1    32
#define C2    16
#define C3    8
#define C4    4
#define NOUT  256
#define KFC   8192
#define NODES 128
#define GF_SIZE (BATCH * NODES * CIN)

__device__ __forceinline__ float bflo(uint32_t p) { return __uint_as_float(p << 16); }
__device__ __forceinline__ float bfhi(uint32_t p) { return __uint_as_float(p & 0xffff0000u); }
__device__ __forceinline__ uint32_t f2bf(float f) {
  uint32_t u = __float_as_uint(f);
  return (u + 0x7fffu + ((u >> 16) & 1u)) >> 16;
}
__device__ __forceinline__ uint32_t packbf(float a, float b) { return f2bf(a) | (f2bf(b) << 16); }

// ---------------------------------------------------------------------------
// K1: conv1 (1x1, 64->32, relu) + conv2 (3x3 pad1, 32->16, relu), fused.
// x NCHW fp32 -> h2 NHWC fp32 [cb][32][64][16]
// grid (4, cb), block 256. Tile = 8 output rows (needs 10 h1 rows).
// LDS: h1 tile as packed bf16 pairs [10][64][17 u32] (68 B lane stride ->
// conflict-free), weights in a reused union buffer (w11 then w12).
// ---------------------------------------------------------------------------
__global__ __launch_bounds__(256) void k_conv12(
    const float* __restrict__ x, const float* __restrict__ w11, const float* __restrict__ b11,
    const float* __restrict__ w12, const float* __restrict__ b12,
    float* __restrict__ h2, int b0)
{
  __shared__ uint32_t h1s[10][64][17];
  __shared__ float __align__(16) wsu[4608];   // union: w11 [c][o] (2048) then w12 [tap][cp][o][2] (4608)
  const int tid = threadIdx.x;
  const int r0  = blockIdx.x * 8;
  const int bg  = b0 + blockIdx.y;

  // stage w11 transposed to [c][32]
  for (int i = tid; i < C1 * CIN; i += 256) wsu[(i & 63) * 32 + (i >> 6)] = w11[i];
  __syncthreads();

  const float* xb = x + (size_t)bg * CIN * HW;

  // phase 1: h1 rows r0-1 .. r0+8 (10 rows x 64 cols)
  for (int p = tid; p < 640; p += 256) {
    const int ry = p >> 6;
    const int wc = p & 63;
    const int y  = r0 - 1 + ry;
    uint32_t* hw = &h1s[ry][wc][0];
    if (y >= 0 && y < HH) {
      float acc[C1];
      #pragma unroll
      for (int o = 0; o < C1; ++o) acc[o] = b11[o];
      const float* xp = xb + y * WW + wc;
      #pragma unroll 4
      for (int c = 0; c < CIN; ++c) {
        float xv = xp[(size_t)c * HW];
        const float4* wr = (const float4*)&wsu[c * 32];
        #pragma unroll
        for (int j = 0; j < 8; ++j) {
          float4 w4 = wr[j];
          acc[4*j+0] = fmaf(xv, w4.x, acc[4*j+0]);
          acc[4*j+1] = fmaf(xv, w4.y, acc[4*j+1]);
          acc[4*j+2] = fmaf(xv, w4.z, acc[4*j+2]);
          acc[4*j+3] = fmaf(xv, w4.w, acc[4*j+3]);
        }
      }
      #pragma unroll
      for (int j = 0; j < 16; ++j)
        hw[j] = packbf(fmaxf(acc[2*j], 0.f), fmaxf(acc[2*j+1], 0.f));
    } else {
      #pragma unroll
      for (int j = 0; j < 16; ++j) hw[j] = 0u;
    }
  }
  __syncthreads();

  // stage w12 into [tap][cpair][o][2] layout
  for (int i = tid; i < C2 * C1 * 9; i += 256) {
    int o = i / 288, r = i - o * 288, c = r / 9, tap = r - c * 9;
    wsu[(tap * 16 + (c >> 1)) * 32 + o * 2 + (c & 1)] = w12[i];
  }
  __syncthreads();

  // phase 2: conv2 on 8x64 outputs, 2 px/thread (rows ry0 and ry0+4)
  {
    const int wc  = tid & 63;
    const int ry0 = (tid >> 6) + 1;   // 1..4 in h1s
    float acc0[C2], acc1[C2];
    #pragma unroll
    for (int o = 0; o < C2; ++o) { float bb = b12[o]; acc0[o] = bb; acc1[o] = bb; }
    #pragma unroll
    for (int ky = 0; ky < 3; ++ky) {
      #pragma unroll
      for (int kx = 0; kx < 3; ++kx) {
        const int wcc = wc + kx - 1;
        if (wcc < 0 || wcc >= WW) continue;
        const uint32_t* hp0 = &h1s[ry0 + ky - 1][wcc][0];
        const uint32_t* hp1 = &h1s[ry0 + 3 + ky][wcc][0];
        const float4* wp = (const float4*)&wsu[(ky * 3 + kx) * 512];
        #pragma unroll
        for (int cp = 0; cp < 16; ++cp) {
          uint32_t p0 = hp0[cp], p1 = hp1[cp];
          float l0 = bflo(p0), g0 = bfhi(p0);
          float l1 = bflo(p1), g1 = bfhi(p1);
          #pragma unroll
          for (int j = 0; j < 8; ++j) {
            float4 w4 = wp[cp * 8 + j];
            acc0[2*j]   = fmaf(l0, w4.x, fmaf(g0, w4.y, acc0[2*j]));
            acc0[2*j+1] = fmaf(l0, w4.z, fmaf(g0, w4.w, acc0[2*j+1]));
            acc1[2*j]   = fmaf(l1, w4.x, fmaf(g1, w4.y, acc1[2*j]));
            acc1[2*j+1] = fmaf(l1, w4.z, fmaf(g1, w4.w, acc1[2*j+1]));
          }
        }
      }
    }
    float* o0 = h2 + (((size_t)blockIdx.y * HH + (r0 + ry0 - 1)) * WW + wc) * C2;
    float* o1 = o0 + (size_t)4 * WW * C2;
    #pragma unroll
    for (int o = 0; o < C2; ++o) o0[o] = fmaxf(acc0[o], 0.f);
    #pragma unroll
    for (int o = 0; o < C2; ++o) o1[o] = fmaxf(acc1[o], 0.f);
  }
}

// ---------------------------------------------------------------------------
// K2: conv3 (1x1, 16->8, relu) + conv4 (3x3 pad1, 8->4, relu), fused.
// h2 NHWC fp32 -> h4 NCHW fp32 [cb][4][32][64]  (matches FC flatten order)
// grid (2, cb), block 256. Tile = 16 output rows (needs 18 h3 rows).
// ---------------------------------------------------------------------------
__global__ __launch_bounds__(256) void k_conv34(
    const float* __restrict__ h2, const float* __restrict__ w21, const float* __restrict__ b21,
    const float* __restrict__ w22, const float* __restrict__ b22, float* __restrict__ h4)
{
  __shared__ float h3s[18][64][9];             // pad 9 -> conflict-free
  __shared__ float __align__(16) w21s[128];    // [c][o]
  __shared__ float __align__(16) w22s[288];    // [tap][c][o]
  const int tid = threadIdx.x;
  const int r0  = blockIdx.x * 16;
  const size_t b = blockIdx.y;

  for (int i = tid; i < 128; i += 256) w21s[(i & 15) * 8 + (i >> 4)] = w21[i];
  for (int i = tid; i < 288; i += 256) {
    int o = i / 72, r = i - o * 72, c = r / 9, tap = r - c * 9;
    w22s[(tap * 8 + c) * 4 + o] = w22[i];
  }
  __syncthreads();

  // phase 1: h3 rows r0-1 .. r0+16
  for (int p = tid; p < 18 * 64; p += 256) {
    const int ry = p >> 6, wc = p & 63;
    const int y  = r0 - 1 + ry;
    float* hd = &h3s[ry][wc][0];
    if (y >= 0 && y < HH) {
      const float4* hp = (const float4*)(h2 + ((b * HH + y) * WW + wc) * C2);
      float4 v0 = hp[0], v1 = hp[1], v2 = hp[2], v3 = hp[3];
      float xv[16] = {v0.x, v0.y, v0.z, v0.w, v1.x, v1.y, v1.z, v1.w,
                      v2.x, v2.y, v2.z, v2.w, v3.x, v3.y, v3.z, v3.w};
      float acc[C3];
      #pragma unroll
      for (int o = 0; o < C3; ++o) acc[o] = b21[o];
      #pragma unroll
      for (int c = 0; c < 16; ++c) {
        const float4* wr = (const float4*)&w21s[c * 8];
        float4 a = wr[0], d = wr[1];
        float v = xv[c];
        acc[0] = fmaf(v, a.x, acc[0]); acc[1] = fmaf(v, a.y, acc[1]);
        acc[2] = fmaf(v, a.z, acc[2]); acc[3] = fmaf(v, a.w, acc[3]);
        acc[4] = fmaf(v, d.x, acc[4]); acc[5] = fmaf(v, d.y, acc[5]);
        acc[6] = fmaf(v, d.z, acc[6]); acc[7] = fmaf(v, d.w, acc[7]);
      }
      #pragma unroll
      for (int c = 0; c < C3; ++c) hd[c] = fmaxf(acc[c], 0.f);
    } else {
      #pragma unroll
      for (int c = 0; c < C3; ++c) hd[c] = 0.f;
    }
  }
  __syncthreads();

  // phase 2: conv4, 4 px/thread
  for (int p = tid; p < 1024; p += 256) {
    const int yl = p >> 6, wc = p & 63, ry = yl + 1;
    float acc[C4] = {b22[0], b22[1], b22[2], b22[3]};
    #pragma unroll
    for (int ky = 0; ky < 3; ++ky) {
      #pragma unroll
      for (int kx = 0; kx < 3; ++kx) {
        const int wcc = wc + kx - 1;
        if (wcc < 0 || wcc >= WW) continue;
        const float* hb = &h3s[ry + ky - 1][wcc][0];
        const int tap = ky * 3 + kx;
        #pragma unroll
        for (int c = 0; c < C3; ++c) {
          float v = hb[c];
          float4 w4 = *(const float4*)&w22s[(tap * 8 + c) * 4];
          acc[0] = fmaf(v, w4.x, acc[0]); acc[1] = fmaf(v, w4.y, acc[1]);
          acc[2] = fmaf(v, w4.z, acc[2]); acc[3] = fmaf(v, w4.w, acc[3]);
        }
      }
    }
    float* op = h4 + (b * C4 * HH + (r0 + yl)) * WW + wc;
    #pragma unroll
    for (int o = 0; o < C4; ++o) op[(size_t)o * HH * WW] = fmaxf(acc[o], 0.f);
  }
}

// ---------------------------------------------------------------------------
// K3: FC GEMM  z[b][o] partials: A = h4 [cb][8192], B = fcw [256][8192]
// 64x64 tiles, K split 8-way -> zpart[kb][b][o] (deterministic, no atomics)
// grid (ceil(cb/64), 4, 8), block 256.
// ---------------------------------------------------------------------------
__global__ __launch_bounds__(256) void k_fc(
    const float* __restrict__ A, const float* __restrict__ Bw,
    float* __restrict__ zpart, int cb)
{
  __shared__ float As[16][68];
  __shared__ float Bs[16][68];
  const int tid = threadIdx.x;
  const int m0 = blockIdx.x * 64;
  const int n0 = blockIdx.y * 64;
  const int k0 = blockIdx.z * 1024;
  const int row = tid >> 2;
  const int q   = tid & 3;
  const int ty  = tid >> 4, tx = tid & 15;
  const int am  = m0 + row;
  const bool aok = (am < cb);
  const float* Ap = A  + (size_t)am * KFC + k0 + q * 4;
  const float* Bp = Bw + (size_t)(n0 + row) * KFC + k0 + q * 4;
  float acc[4][4] = {};

  for (int ks = 0; ks < 64; ++ks) {
    float4 av = aok ? *(const float4*)Ap : float4{0.f, 0.f, 0.f, 0.f};
    float4 bv = *(const float4*)Bp;
    __syncthreads();
    As[q*4+0][row] = av.x; As[q*4+1][row] = av.y; As[q*4+2][row] = av.z; As[q*4+3][row] = av.w;
    Bs[q*4+0][row] = bv.x; Bs[q*4+1][row] = bv.y; Bs[q*4+2][row] = bv.z; Bs[q*4+3][row] = bv.w;
    __syncthreads();
    #pragma unroll
    for (int kk = 0; kk < 16; ++kk) {
      float4 a4 = *(const float4*)&As[kk][ty * 4];
      float4 b4 = *(const float4*)&Bs[kk][tx * 4];
      acc[0][0] = fmaf(a4.x, b4.x, acc[0][0]); acc[0][1] = fmaf(a4.x, b4.y, acc[0][1]);
      acc[0][2] = fmaf(a4.x, b4.z, acc[0][2]); acc[0][3] = fmaf(a4.x, b4.w, acc[0][3]);
      acc[1][0] = fmaf(a4.y, b4.x, acc[1][0]); acc[1][1] = fmaf(a4.y, b4.y, acc[1][1]);
      acc[1][2] = fmaf(a4.y, b4.z, acc[1][2]); acc[1][3] = fmaf(a4.y, b4.w, acc[1][3]);
      acc[2][0] = fmaf(a4.z, b4.x, acc[2][0]); acc[2][1] = fmaf(a4.z, b4.y, acc[2][1]);
      acc[2][2] = fmaf(a4.z, b4.z, acc[2][2]); acc[2][3] = fmaf(a4.z, b4.w, acc[2][3]);
      acc[3][0] = fmaf(a4.w, b4.x, acc[3][0]); acc[3][1] = fmaf(a4.w, b4.y, acc[3][1]);
      acc[3][2] = fmaf(a4.w, b4.z, acc[3][2]); acc[3][3] = fmaf(a4.w, b4.w, acc[3][3]);
    }
    Ap += 16; Bp += 16;
  }

  #pragma unroll
  for (int i = 0; i < 4; ++i) {
    int m = m0 + ty * 4 + i;
    if (m < cb) {
      size_t base = ((size_t)blockIdx.z * cb + m) * NOUT + n0 + tx * 4;
      #pragma unroll
      for (int j = 0; j < 4; ++j) zpart[base + j] = acc[i][j];
    }
  }
}

// ---------------------------------------------------------------------------
// K4: reduce K-split partials + bias -> sigmoid(3z) -> coord, write coord out
// ---------------------------------------------------------------------------
__global__ __launch_bounds__(256) void k_coord(
    const float* __restrict__ zpart, const float* __restrict__ fcb,
    float* __restrict__ out, int cb, int b0)
{
  const int b = blockIdx.x;
  const int o = threadIdx.x;
  float z = fcb[o];
  #pragma unroll
  for (int kb = 0; kb < 8; ++kb) z += zpart[((size_t)kb * cb + b) * NOUT + o];
  float s = 1.f / (1.f + __expf(-3.f * z));
  const int node = o >> 1, comp = o & 1;
  out[GF_SIZE + (((size_t)(b0 + b) * NODES + node) << 1) + comp] = s * (comp ? 63.f : 31.f);
}

// ---------------------------------------------------------------------------
// K5: bilinear gather. One 64-lane group per (b,node); lane = channel.
// ---------------------------------------------------------------------------
__global__ __launch_bounds__(256) void k_gather(
    const float* __restrict__ x, float* __restrict__ out, int b0)
{
  const int pair = blockIdx.x * 4 + (threadIdx.x >> 6);
  const int c    = threadIdx.x & 63;
  const int bl   = pair >> 7;
  const int node = pair & 127;
  const int bg   = b0 + bl;
  const float* cp = out + GF_SIZE + ((size_t)bg * NODES + node) * 2;
  float chv = fminf(fmaxf(cp[0], 0.f), 31.f);
  float cwv = fminf(fmaxf(cp[1], 0.f), 63.f);
  float fh = floorf(chv), fw = floorf(cwv);
  int h0 = (int)fh, h1i = (int)ceilf(chv);
  int w0 = (int)fw, w1i = (int)ceilf(cwv);
  float oh = chv - fh, ow = cwv - fw;
  const float* xb = x + ((size_t)bg * CIN + c) * HW;
  float v_lt = xb[h0 * WW + w0];
  float v_rt = xb[h1i * WW + w0];
  float v_lb = xb[h0 * WW + w1i];
  float v_rb = xb[h1i * WW + w1i];
  float vt = v_lt + oh * (v_rt - v_lt);
  float vb = v_lb + oh * (v_rb - v_lb);
  out[((size_t)bg * NODES + node) * CIN + c] = vt + ow * (vb - vt);
}

// ---------------------------------------------------------------------------
extern "C" void kernel_launch(void* const* d_in, const int* in_sizes, int n_in,
                              void* d_out, int out_size, void* d_ws, size_t ws_size,
                              hipStream_t stream)
{
  (void)in_sizes; (void)n_in; (void)out_size;
  const float* x   = (const float*)d_in[0];
  const float* w11 = (const float*)d_in[1];
  const float* b11 = (const float*)d_in[2];
  const float* w12 = (const float*)d_in[3];
  const float* b12 = (const float*)d_in[4];
  const float* w21 = (const float*)d_in[5];
  const float* b21 = (const float*)d_in[6];
  const float* w22 = (const float*)d_in[7];
  const float* b22 = (const float*)d_in[8];
  const float* fcw = (const float*)d_in[9];
  const float* fcb = (const float*)d_in[10];
  float* out = (float*)d_out;
  char* wsb  = (char*)d_ws;

  // per-b workspace: h2 (NHWC f32) + h4 (NCHW f32) + 8x z partials
  const size_t perB = (size_t)HH * WW * C2 * 4 + (size_t)C4 * HW * 4 + 8 * NOUT * 4; // 172032 B
  size_t cbmax = ws_size / perB;
  int CB = (int)(cbmax < (size_t)BATCH ? cbmax : (size_t)BATCH);
  if (CB < 1) CB = 1;

  float* h2v = (float*)wsb;
  float* h4v = (float*)(wsb + (size_t)CB * HH * WW * C2 * 4);
  float* zpv = (float*)(wsb + (size_t)CB * HH * WW * C2 * 4 + (size_t)CB * C4 * HW * 4);

  for (int b0 = 0; b0 < BATCH; b0 += CB) {
    const int cb = (BATCH - b0 < CB) ? (BATCH - b0) : CB;
    k_conv12<<<dim3(4, cb), 256, 0, stream>>>(x, w11, b11, w12, b12, h2v, b0);
    k_conv34<<<dim3(2, cb), 256, 0, stream>>>(h2v, w21, b21, w22, b22, h4v);
    k_fc<<<dim3((cb + 63) / 64, 4, 8), 256, 0, stream>>>(h4v, fcw, zpv, cb);
    k_coord<<<dim3(cb), 256, 0, stream>>>(zpv, fcb, out, cb, b0);
    k_gather<<<dim3(cb * 32), 256, 0, stream>>>(x, out, b0);
  }
}

// Round 2
// 312.923 us; speedup vs baseline: 2.5693x; 2.5693x over previous
//
#include <hip/hip_runtime.h>
#include <cstdint>

#define BATCH 512
#define CIN   64
#define HH    32
#define WW    64
#define HW    2048
#define C1    32
#define C2    16
#define C3    8
#define C4    4
#define NOUT  256
#define KFC   8192
#define NODES 128
#define GF_SIZE (BATCH * NODES * CIN)

typedef __attribute__((ext_vector_type(8))) short bfrag;   // 8 bf16 (4 VGPRs)
typedef __attribute__((ext_vector_type(4))) float ffrag;   // 4 fp32 acc

__device__ __forceinline__ ushort bf_trunc(float f) { return (ushort)(__float_as_uint(f) >> 16); }
__device__ __forceinline__ float  bf_truncf(float f) { return __uint_as_float(__float_as_uint(f) & 0xffff0000u); }
__device__ __forceinline__ ushort f2bf(float f) {
  uint32_t u = __float_as_uint(f);
  return (ushort)((u + 0x7fffu + ((u >> 16) & 1u)) >> 16);
}
__device__ __forceinline__ uint32_t pack2(float a, float b) {
  return (uint32_t)f2bf(a) | ((uint32_t)f2bf(b) << 16);
}

// ---------------------------------------------------------------------------
// K1: conv1 (1x1, 64->32) + conv2 (3x3 pad1, 32->16) fused, MFMA bf16.
// Split-precision: conv1 uses (Whi*xhi + Whi*xlo + Wlo*xhi) ~= fp32 exact;
// h1 stored as RTN bf16 (same as prior passing version); conv2 uses
// (W2hi + W2lo) * h1_bf16 == fp32-W x bf16-h (same error as prior version).
// x NCHW fp32 -> h2 NHWC fp32 [cb][32][64][16]
// grid (4, cb), block 256 (4 waves). Tile = 8 output rows (10 h1 rows).
// LDS: h1 [10 rows][66 cols(pad)][32c bf16], 16B-chunk XOR-swizzled by
// ((colb>>1)&3) -> 2-way bank aliasing (free). + W2 hi/lo frag layout.
// ---------------------------------------------------------------------------
__global__ __launch_bounds__(256) void k_conv12(
    const float* __restrict__ x, const float* __restrict__ w11, const float* __restrict__ b11,
    const float* __restrict__ w12, const float* __restrict__ b12,
    float* __restrict__ h2, int b0)
{
  __shared__ __align__(16) char   h1s[10 * 66 * 64];       // 42240 B
  __shared__ __align__(16) ushort w2s[2][9][16][32];       // 18432 B
  const int tid = threadIdx.x;
  const int l   = tid & 63;
  const int wv  = tid >> 6;
  const int lr  = l & 15;     // A-row / B-col lane index
  const int lg  = l >> 4;     // k-chunk group 0..3
  const int r0  = blockIdx.x * 8;
  const int bg  = b0 + blockIdx.y;
  const float* xb = x + (size_t)bg * CIN * HW;

  // stage W2 (w12 [16][32][3][3]) as hi/lo bf16 in frag-friendly [tap][o2][c]
  for (int i = tid; i < C2 * C1 * 9; i += 256) {
    int o2 = i / 288, rem = i - o2 * 288, c = rem / 9, t = rem - c * 9;
    float v = w12[i];
    w2s[0][t][o2][c] = bf_trunc(v);
    w2s[1][t][o2][c] = f2bf(v - bf_truncf(v));
  }
  // zero the padded columns (colb = 0 and 65) of h1s
  if (tid < 160) {
    int row = tid >> 4, half = (tid >> 3) & 1, q = tid & 7;
    int cell = row * 66 + (half ? 65 : 0);
    *(uint2*)(h1s + (cell << 6) + q * 8) = uint2{0u, 0u};
  }

  // W1 fragments from global (contiguous 8 floats per lane per frag)
  bfrag w1h[2][2], w1l[2][2];   // [Mtile][kstep]
  #pragma unroll
  for (int m = 0; m < 2; ++m) {
    #pragma unroll
    for (int ks = 0; ks < 2; ++ks) {
      const float* wp = w11 + (m * 16 + lr) * 64 + ks * 32 + lg * 8;
      #pragma unroll
      for (int e = 0; e < 8; ++e) {
        float v = wp[e];
        w1h[m][ks][e] = (short)bf_trunc(v);
        w1l[m][ks][e] = (short)f2bf(v - bf_truncf(v));
      }
    }
  }
  float bias1[2][4];
  #pragma unroll
  for (int m = 0; m < 2; ++m) {
    #pragma unroll
    for (int r = 0; r < 4; ++r) bias1[m][r] = b11[m * 16 + lg * 4 + r];
  }

  // ---- Phase A: conv1 -> h1 LDS (10 N-tiles of 16 px per wave) ----
  #pragma unroll 2
  for (int i = 0; i < 10; ++i) {
    const int nt   = wv * 10 + i;
    const int ry   = nt >> 2;
    const int col0 = (nt & 3) << 4;
    const int y    = r0 - 1 + ry;
    const int colb = col0 + 1 + lr;
    if (y >= 0 && y < HH) {
      float xv[16];
      const float* xp = xb + y * WW + col0 + lr;
      #pragma unroll
      for (int ks = 0; ks < 2; ++ks) {
        #pragma unroll
        for (int e = 0; e < 8; ++e)
          xv[ks * 8 + e] = xp[(size_t)(ks * 32 + lg * 8 + e) * HW];
      }
      bfrag xh[2], xl[2];
      #pragma unroll
      for (int ks = 0; ks < 2; ++ks) {
        #pragma unroll
        for (int e = 0; e < 8; ++e) {
          float v = xv[ks * 8 + e];
          xh[ks][e] = (short)bf_trunc(v);
          xl[ks][e] = (short)f2bf(v - bf_truncf(v));
        }
      }
      ffrag a0 = {0.f, 0.f, 0.f, 0.f}, a1 = {0.f, 0.f, 0.f, 0.f};
      #pragma unroll
      for (int ks = 0; ks < 2; ++ks) {
        a0 = __builtin_amdgcn_mfma_f32_16x16x32_bf16(w1h[0][ks], xh[ks], a0, 0, 0, 0);
        a0 = __builtin_amdgcn_mfma_f32_16x16x32_bf16(w1h[0][ks], xl[ks], a0, 0, 0, 0);
        a0 = __builtin_amdgcn_mfma_f32_16x16x32_bf16(w1l[0][ks], xh[ks], a0, 0, 0, 0);
        a1 = __builtin_amdgcn_mfma_f32_16x16x32_bf16(w1h[1][ks], xh[ks], a1, 0, 0, 0);
        a1 = __builtin_amdgcn_mfma_f32_16x16x32_bf16(w1h[1][ks], xl[ks], a1, 0, 0, 0);
        a1 = __builtin_amdgcn_mfma_f32_16x16x32_bf16(w1l[1][ks], xh[ks], a1, 0, 0, 0);
      }
      #pragma unroll
      for (int m = 0; m < 2; ++m) {
        float v0 = fmaxf((m ? a1[0] : a0[0]) + bias1[m][0], 0.f);
        float v1 = fmaxf((m ? a1[1] : a0[1]) + bias1[m][1], 0.f);
        float v2 = fmaxf((m ? a1[2] : a0[2]) + bias1[m][2], 0.f);
        float v3 = fmaxf((m ? a1[3] : a0[3]) + bias1[m][3], 0.f);
        int chunk = (m * 2 + (lg >> 1)) ^ ((colb >> 1) & 3);
        char* dst = h1s + ((ry * 66 + colb) << 6) + (chunk << 4) + (lg & 1) * 8;
        *(uint2*)dst = uint2{pack2(v0, v1), pack2(v2, v3)};
      }
    } else {
      #pragma unroll
      for (int m = 0; m < 2; ++m) {
        int chunk = (m * 2 + (lg >> 1)) ^ ((colb >> 1) & 3);
        char* dst = h1s + ((ry * 66 + colb) << 6) + (chunk << 4) + (lg & 1) * 8;
        *(uint2*)dst = uint2{0u, 0u};
      }
    }
  }
  __syncthreads();

  // ---- Phase B: conv2 (9 taps, K=32) -> h2 global (8 N-tiles per wave) ----
  bfrag w2h[9], w2l[9];
  #pragma unroll
  for (int t = 0; t < 9; ++t) {
    w2h[t] = *(const bfrag*)&w2s[0][t][lr][lg * 8];
    w2l[t] = *(const bfrag*)&w2s[1][t][lr][lg * 8];
  }
  float bias2[4];
  #pragma unroll
  for (int r = 0; r < 4; ++r) bias2[r] = b12[lg * 4 + r];

  #pragma unroll 2
  for (int i = 0; i < 8; ++i) {
    const int nt   = wv * 8 + i;
    const int ryo  = nt >> 2;
    const int col0 = (nt & 3) << 4;
    ffrag acc = {0.f, 0.f, 0.f, 0.f};
    #pragma unroll
    for (int ky = 0; ky < 3; ++ky) {
      const int row = ryo + ky;
      #pragma unroll
      for (int kx = 0; kx < 3; ++kx) {
        const int colb  = col0 + lr + kx;
        const int chunk = lg ^ ((colb >> 1) & 3);
        const bfrag hv = *(const bfrag*)(h1s + ((row * 66 + colb) << 6) + (chunk << 4));
        acc = __builtin_amdgcn_mfma_f32_16x16x32_bf16(w2h[ky * 3 + kx], hv, acc, 0, 0, 0);
        acc = __builtin_amdgcn_mfma_f32_16x16x32_bf16(w2l[ky * 3 + kx], hv, acc, 0, 0, 0);
      }
    }
    const int px = (r0 + ryo) * WW + col0 + lr;
    float4 o;
    o.x = fmaxf(acc[0] + bias2[0], 0.f);
    o.y = fmaxf(acc[1] + bias2[1], 0.f);
    o.z = fmaxf(acc[2] + bias2[2], 0.f);
    o.w = fmaxf(acc[3] + bias2[3], 0.f);
    *(float4*)(h2 + ((size_t)blockIdx.y * HW + px) * 16 + lg * 4) = o;
  }
}

// ---------------------------------------------------------------------------
// K2: conv3 (1x1, 16->8, relu) + conv4 (3x3 pad1, 8->4, relu), fused (VALU).
// h2 NHWC fp32 -> h4 NCHW fp32 [cb][4][32][64]
// ---------------------------------------------------------------------------
__global__ __launch_bounds__(256) void k_conv34(
    const float* __restrict__ h2, const float* __restrict__ w21, const float* __restrict__ b21,
    const float* __restrict__ w22, const float* __restrict__ b22, float* __restrict__ h4)
{
  __shared__ float h3s[18][64][9];
  __shared__ float __align__(16) w21s[128];
  __shared__ float __align__(16) w22s[288];
  const int tid = threadIdx.x;
  const int r0  = blockIdx.x * 16;
  const size_t b = blockIdx.y;

  for (int i = tid; i < 128; i += 256) w21s[(i & 15) * 8 + (i >> 4)] = w21[i];
  for (int i = tid; i < 288; i += 256) {
    int o = i / 72, r = i - o * 72, c = r / 9, tap = r - c * 9;
    w22s[(tap * 8 + c) * 4 + o] = w22[i];
  }
  __syncthreads();

  for (int p = tid; p < 18 * 64; p += 256) {
    const int ry = p >> 6, wc = p & 63;
    const int y  = r0 - 1 + ry;
    float* hd = &h3s[ry][wc][0];
    if (y >= 0 && y < HH) {
      const float4* hp = (const float4*)(h2 + ((b * HH + y) * WW + wc) * C2);
      float4 v0 = hp[0], v1 = hp[1], v2 = hp[2], v3 = hp[3];
      float xv[16] = {v0.x, v0.y, v0.z, v0.w, v1.x, v1.y, v1.z, v1.w,
                      v2.x, v2.y, v2.z, v2.w, v3.x, v3.y, v3.z, v3.w};
      float acc[C3];
      #pragma unroll
      for (int o = 0; o < C3; ++o) acc[o] = b21[o];
      #pragma unroll
      for (int c = 0; c < 16; ++c) {
        const float4* wr = (const float4*)&w21s[c * 8];
        float4 a = wr[0], d = wr[1];
        float v = xv[c];
        acc[0] = fmaf(v, a.x, acc[0]); acc[1] = fmaf(v, a.y, acc[1]);
        acc[2] = fmaf(v, a.z, acc[2]); acc[3] = fmaf(v, a.w, acc[3]);
        acc[4] = fmaf(v, d.x, acc[4]); acc[5] = fmaf(v, d.y, acc[5]);
        acc[6] = fmaf(v, d.z, acc[6]); acc[7] = fmaf(v, d.w, acc[7]);
      }
      #pragma unroll
      for (int c = 0; c < C3; ++c) hd[c] = fmaxf(acc[c], 0.f);
    } else {
      #pragma unroll
      for (int c = 0; c < C3; ++c) hd[c] = 0.f;
    }
  }
  __syncthreads();

  for (int p = tid; p < 1024; p += 256) {
    const int yl = p >> 6, wc = p & 63, ry = yl + 1;
    float acc[C4] = {b22[0], b22[1], b22[2], b22[3]};
    #pragma unroll
    for (int ky = 0; ky < 3; ++ky) {
      #pragma unroll
      for (int kx = 0; kx < 3; ++kx) {
        const int wcc = wc + kx - 1;
        if (wcc < 0 || wcc >= WW) continue;
        const float* hb = &h3s[ry + ky - 1][wcc][0];
        const int tap = ky * 3 + kx;
        #pragma unroll
        for (int c = 0; c < C3; ++c) {
          float v = hb[c];
          float4 w4 = *(const float4*)&w22s[(tap * 8 + c) * 4];
          acc[0] = fmaf(v, w4.x, acc[0]); acc[1] = fmaf(v, w4.y, acc[1]);
          acc[2] = fmaf(v, w4.z, acc[2]); acc[3] = fmaf(v, w4.w, acc[3]);
        }
      }
    }
    float* op = h4 + (b * C4 * HH + (r0 + yl)) * WW + wc;
    #pragma unroll
    for (int o = 0; o < C4; ++o) op[(size_t)o * HH * WW] = fmaxf(acc[o], 0.f);
  }
}

// ---------------------------------------------------------------------------
// K3: FC GEMM partials (fp32 VALU), K split 8-way, deterministic.
// ---------------------------------------------------------------------------
__global__ __launch_bounds__(256) void k_fc(
    const float* __restrict__ A, const float* __restrict__ Bw,
    float* __restrict__ zpart, int cb)
{
  __shared__ float As[16][68];
  __shared__ float Bs[16][68];
  const int tid = threadIdx.x;
  const int m0 = blockIdx.x * 64;
  const int n0 = blockIdx.y * 64;
  const int k0 = blockIdx.z * 1024;
  const int row = tid >> 2;
  const int q   = tid & 3;
  const int ty  = tid >> 4, tx = tid & 15;
  const int am  = m0 + row;
  const bool aok = (am < cb);
  const float* Ap = A  + (size_t)am * KFC + k0 + q * 4;
  const float* Bp = Bw + (size_t)(n0 + row) * KFC + k0 + q * 4;
  float acc[4][4] = {};

  for (int ks = 0; ks < 64; ++ks) {
    float4 av = aok ? *(const float4*)Ap : float4{0.f, 0.f, 0.f, 0.f};
    float4 bv = *(const float4*)Bp;
    __syncthreads();
    As[q*4+0][row] = av.x; As[q*4+1][row] = av.y; As[q*4+2][row] = av.z; As[q*4+3][row] = av.w;
    Bs[q*4+0][row] = bv.x; Bs[q*4+1][row] = bv.y; Bs[q*4+2][row] = bv.z; Bs[q*4+3][row] = bv.w;
    __syncthreads();
    #pragma unroll
    for (int kk = 0; kk < 16; ++kk) {
      float4 a4 = *(const float4*)&As[kk][ty * 4];
      float4 b4 = *(const float4*)&Bs[kk][tx * 4];
      acc[0][0] = fmaf(a4.x, b4.x, acc[0][0]); acc[0][1] = fmaf(a4.x, b4.y, acc[0][1]);
      acc[0][2] = fmaf(a4.x, b4.z, acc[0][2]); acc[0][3] = fmaf(a4.x, b4.w, acc[0][3]);
      acc[1][0] = fmaf(a4.y, b4.x, acc[1][0]); acc[1][1] = fmaf(a4.y, b4.y, acc[1][1]);
      acc[1][2] = fmaf(a4.y, b4.z, acc[1][2]); acc[1][3] = fmaf(a4.y, b4.w, acc[1][3]);
      acc[2][0] = fmaf(a4.z, b4.x, acc[2][0]); acc[2][1] = fmaf(a4.z, b4.y, acc[2][1]);
      acc[2][2] = fmaf(a4.z, b4.z, acc[2][2]); acc[2][3] = fmaf(a4.z, b4.w, acc[2][3]);
      acc[3][0] = fmaf(a4.w, b4.x, acc[3][0]); acc[3][1] = fmaf(a4.w, b4.y, acc[3][1]);
      acc[3][2] = fmaf(a4.w, b4.z, acc[3][2]); acc[3][3] = fmaf(a4.w, b4.w, acc[3][3]);
    }
    Ap += 16; Bp += 16;
  }

  #pragma unroll
  for (int i = 0; i < 4; ++i) {
    int m = m0 + ty * 4 + i;
    if (m < cb) {
      size_t base = ((size_t)blockIdx.z * cb + m) * NOUT + n0 + tx * 4;
      #pragma unroll
      for (int j = 0; j < 4; ++j) zpart[base + j] = acc[i][j];
    }
  }
}

// ---------------------------------------------------------------------------
// K4: reduce partials + bias -> sigmoid(3z) -> coord
// ---------------------------------------------------------------------------
__global__ __launch_bounds__(256) void k_coord(
    const float* __restrict__ zpart, const float* __restrict__ fcb,
    float* __restrict__ out, int cb, int b0)
{
  const int b = blockIdx.x;
  const int o = threadIdx.x;
  float z = fcb[o];
  #pragma unroll
  for (int kb = 0; kb < 8; ++kb) z += zpart[((size_t)kb * cb + b) * NOUT + o];
  float s = 1.f / (1.f + __expf(-3.f * z));
  const int node = o >> 1, comp = o & 1;
  out[GF_SIZE + (((size_t)(b0 + b) * NODES + node) << 1) + comp] = s * (comp ? 63.f : 31.f);
}

// ---------------------------------------------------------------------------
// K5: bilinear gather. One 64-lane group per (b,node); lane = channel.
// ---------------------------------------------------------------------------
__global__ __launch_bounds__(256) void k_gather(
    const float* __restrict__ x, float* __restrict__ out, int b0)
{
  const int pair = blockIdx.x * 4 + (threadIdx.x >> 6);
  const int c    = threadIdx.x & 63;
  const int bl   = pair >> 7;
  const int node = pair & 127;
  const int bg   = b0 + bl;
  const float* cp = out + GF_SIZE + ((size_t)bg * NODES + node) * 2;
  float chv = fminf(fmaxf(cp[0], 0.f), 31.f);
  float cwv = fminf(fmaxf(cp[1], 0.f), 63.f);
  float fh = floorf(chv), fw = floorf(cwv);
  int h0 = (int)fh, h1i = (int)ceilf(chv);
  int w0 = (int)fw, w1i = (int)ceilf(cwv);
  float oh = chv - fh, ow = cwv - fw;
  const float* xb = x + ((size_t)bg * CIN + c) * HW;
  float v_lt = xb[h0 * WW + w0];
  float v_rt = xb[h1i * WW + w0];
  float v_lb = xb[h0 * WW + w1i];
  float v_rb = xb[h1i * WW + w1i];
  float vt = v_lt + oh * (v_rt - v_lt);
  float vb = v_lb + oh * (v_rb - v_lb);
  out[((size_t)bg * NODES + node) * CIN + c] = vt + ow * (vb - vt);
}

// ---------------------------------------------------------------------------
extern "C" void kernel_launch(void* const* d_in, const int* in_sizes, int n_in,
                              void* d_out, int out_size, void* d_ws, size_t ws_size,
                              hipStream_t stream)
{
  (void)in_sizes; (void)n_in; (void)out_size;
  const float* x   = (const float*)d_in[0];
  const float* w11 = (const float*)d_in[1];
  const float* b11 = (const float*)d_in[2];
  const float* w12 = (const float*)d_in[3];
  const float* b12 = (const float*)d_in[4];
  const float* w21 = (const float*)d_in[5];
  const float* b21 = (const float*)d_in[6];
  const float* w22 = (const float*)d_in[7];
  const float* b22 = (const float*)d_in[8];
  const float* fcw = (const float*)d_in[9];
  const float* fcb = (const float*)d_in[10];
  float* out = (float*)d_out;
  char* wsb  = (char*)d_ws;

  const size_t perB = (size_t)HH * WW * C2 * 4 + (size_t)C4 * HW * 4 + 8 * NOUT * 4; // 172032 B
  size_t cbmax = ws_size / perB;
  int CB = (int)(cbmax < (size_t)BATCH ? cbmax : (size_t)BATCH);
  if (CB < 1) CB = 1;

  float* h2v = (float*)wsb;
  float* h4v = (float*)(wsb + (size_t)CB * HH * WW * C2 * 4);
  float* zpv = (float*)(wsb + (size_t)CB * HH * WW * C2 * 4 + (size_t)CB * C4 * HW * 4);

  for (int b0 = 0; b0 < BATCH; b0 += CB) {
    const int cb = (BATCH - b0 < CB) ? (BATCH - b0) : CB;
    k_conv12<<<dim3(4, cb), 256, 0, stream>>>(x, w11, b11, w12, b12, h2v, b0);
    k_conv34<<<dim3(2, cb), 256, 0, stream>>>(h2v, w21, b21, w22, b22, h4v);
    k_fc<<<dim3((cb + 63) / 64, 4, 8), 256, 0, stream>>>(h4v, fcw, zpv, cb);
    k_coord<<<dim3(cb), 256, 0, stream>>>(zpv, fcb, out, cb, b0);
    k_gather<<<dim3(cb * 32), 256, 0, stream>>>(x, out, b0);
  }
}